// Round 1
// baseline (792.723 us; speedup 1.0000x reference)
//
#include <hip/hip_runtime.h>
#include <math.h>

#define BB 8
#define SS 2048
#define EE 1024
#define HH 64
#define MM (BB * SS)   // 16384 rows

// ---------------------------------------------------------------------------
// Projection GEMM: out[M x 64] = A[M x 1024] @ W[1024 x 64] + bias
// Tile: 64 rows x 64 cols, K-chunk 32. 256 threads as 16x16, 4x4 micro-tile.
// ---------------------------------------------------------------------------
#define PM 64
#define PK 32

__global__ __launch_bounds__(256) void proj_kernel(
    const float* __restrict__ A0, const float* __restrict__ A1, const float* __restrict__ A2,
    const float* __restrict__ W0, const float* __restrict__ W1, const float* __restrict__ W2,
    const float* __restrict__ b0, const float* __restrict__ b1, const float* __restrict__ b2,
    float* __restrict__ o0, float* __restrict__ o1, float* __restrict__ o2)
{
    const int which = blockIdx.y;
    const float* __restrict__ A    = (which == 0) ? A0 : (which == 1) ? A1 : A2;
    const float* __restrict__ W    = (which == 0) ? W0 : (which == 1) ? W1 : W2;
    const float* __restrict__ bias = (which == 0) ? b0 : (which == 1) ? b1 : b2;
    float* __restrict__ out        = (which == 0) ? o0 : (which == 1) ? o1 : o2;

    // As pad 36: compute-read banks for ty in {0..3}: offsets {0,16,0,16} -> 2-way (free)
    __shared__ __align__(16) float As[PM][PK + 4];   // 64 x 36
    __shared__ __align__(16) float Ws[PK][HH + 4];   // 32 x 68

    const int row0 = blockIdx.x * PM;
    const int tid  = threadIdx.x;
    const int tx   = tid & 15;        // 0..15 -> output cols tx*4..tx*4+3
    const int ty   = tid >> 4;        // 0..15 -> output rows ty*4..ty*4+3

    float acc[4][4];
    #pragma unroll
    for (int i = 0; i < 4; ++i)
        #pragma unroll
        for (int j = 0; j < 4; ++j) acc[i][j] = 0.f;

    for (int kc = 0; kc < EE; kc += PK) {
        // A chunk: 64 x 32 floats = 512 float4 (2 per thread), coalesced
        #pragma unroll
        for (int e4 = tid; e4 < PM * PK / 4; e4 += 256) {
            int r = e4 >> 3;               // 8 float4 per 32-wide row
            int c = (e4 & 7) << 2;
            *(float4*)&As[r][c] =
                *(const float4*)&A[(size_t)(row0 + r) * EE + kc + c];
        }
        // W chunk: 32 x 64 floats = 512 float4 (2 per thread), coalesced
        #pragma unroll
        for (int e4 = tid; e4 < PK * HH / 4; e4 += 256) {
            int r = e4 >> 4;               // 16 float4 per 64-wide row
            int c = (e4 & 15) << 2;
            *(float4*)&Ws[r][c] =
                *(const float4*)&W[(size_t)(kc + r) * HH + c];
        }
        __syncthreads();

        #pragma unroll
        for (int kk = 0; kk < PK; ++kk) {
            float a[4];
            #pragma unroll
            for (int i = 0; i < 4; ++i) a[i] = As[ty * 4 + i][kk];  // broadcast reads
            const float4 w4 = *(const float4*)&Ws[kk][tx * 4];
            #pragma unroll
            for (int i = 0; i < 4; ++i) {
                acc[i][0] = fmaf(a[i], w4.x, acc[i][0]);
                acc[i][1] = fmaf(a[i], w4.y, acc[i][1]);
                acc[i][2] = fmaf(a[i], w4.z, acc[i][2]);
                acc[i][3] = fmaf(a[i], w4.w, acc[i][3]);
            }
        }
        __syncthreads();
    }

    const float4 b4 = *(const float4*)&bias[tx * 4];
    #pragma unroll
    for (int i = 0; i < 4; ++i) {
        float4 o;
        o.x = acc[i][0] + b4.x;
        o.y = acc[i][1] + b4.y;
        o.z = acc[i][2] + b4.z;
        o.w = acc[i][3] + b4.w;
        *(float4*)&out[(size_t)(row0 + ty * 4 + i) * HH + tx * 4] = o;
    }
}

// ---------------------------------------------------------------------------
// Flash attention, fp32. One block per (batch, 64-row Q tile). 512 threads =
// 8 waves; wave w owns Q rows w*8..w*8+7. Scores: lane = key j (XOR-swizzled
// K tile in LDS, 2-way bank aliasing = free). PV: lane = head h, P broadcast
// via __shfl with uniform source lane (v_readlane).
// ---------------------------------------------------------------------------
#define BQ 64
#define BK 64

__global__ __launch_bounds__(512) void flash_kernel(
    const float* __restrict__ qp, const float* __restrict__ kp,
    const float* __restrict__ vp, float* __restrict__ out)
{
    __shared__ __align__(16) float Qs[BQ * HH];   // broadcast reads only: no pad
    __shared__ __align__(16) float Ks[BK * HH];   // xor-swizzled
    __shared__ __align__(16) float Vs[BK * HH];   // lane-consecutive reads: no pad

    const int b    = blockIdx.y;
    const int q0   = blockIdx.x * BQ;
    const int tid  = threadIdx.x;
    const int lane = tid & 63;
    const int wave = tid >> 6;     // 0..7

    const float* __restrict__ qbase = qp + ((size_t)b * SS + q0) * HH;
    for (int t = tid; t < BQ * HH; t += 512) Qs[t] = qbase[t];

    float m_i[8], l_i[8], Oa[8];
    #pragma unroll
    for (int i = 0; i < 8; ++i) { m_i[i] = -1e30f; l_i[i] = 0.f; Oa[i] = 0.f; }

    const float* __restrict__ kbase = kp + (size_t)b * SS * HH;
    const float* __restrict__ vbase = vp + (size_t)b * SS * HH;
    const int sw   = lane & 31;
    const int krow = lane << 6;

    for (int kt = 0; kt < SS; kt += BK) {
        __syncthreads();   // previous iteration finished reading Ks/Vs
        for (int t = tid; t < BK * HH; t += 512) {
            int j = t >> 6, h = t & 63;
            Ks[(j << 6) | (h ^ (j & 31))] = kbase[(size_t)kt * HH + t];
            Vs[t]                         = vbase[(size_t)kt * HH + t];
        }
        __syncthreads();

        // --- scores: s[i] = q_row(i) . k_lane  -------------------------------
        float s[8];
        #pragma unroll
        for (int i = 0; i < 8; ++i) s[i] = 0.f;
        #pragma unroll
        for (int h = 0; h < HH; h += 4) {
            const float k0 = Ks[krow | ((h + 0) ^ sw)];
            const float k1 = Ks[krow | ((h + 1) ^ sw)];
            const float k2 = Ks[krow | ((h + 2) ^ sw)];
            const float k3 = Ks[krow | ((h + 3) ^ sw)];
            #pragma unroll
            for (int i = 0; i < 8; ++i) {
                const float4 q4 = *(const float4*)&Qs[((wave * 8 + i) << 6) + h];
                s[i] = fmaf(q4.x, k0, s[i]);
                s[i] = fmaf(q4.y, k1, s[i]);
                s[i] = fmaf(q4.z, k2, s[i]);
                s[i] = fmaf(q4.w, k3, s[i]);
            }
        }

        // --- online softmax over the 64 keys held across lanes ---------------
        float t_new[8];
        #pragma unroll
        for (int i = 0; i < 8; ++i) { s[i] *= 0.125f; t_new[i] = s[i]; }
        #pragma unroll
        for (int off = 32; off >= 1; off >>= 1)
            #pragma unroll
            for (int i = 0; i < 8; ++i)
                t_new[i] = fmaxf(t_new[i], __shfl_xor(t_new[i], off, 64));

        float p[8], alpha[8];
        #pragma unroll
        for (int i = 0; i < 8; ++i) {
            const float mn = fmaxf(m_i[i], t_new[i]);
            alpha[i] = __expf(m_i[i] - mn);
            m_i[i]   = mn;
            p[i]     = __expf(s[i] - mn);
        }

        float ps[8];
        #pragma unroll
        for (int i = 0; i < 8; ++i) ps[i] = p[i];
        #pragma unroll
        for (int off = 32; off >= 1; off >>= 1)
            #pragma unroll
            for (int i = 0; i < 8; ++i)
                ps[i] += __shfl_xor(ps[i], off, 64);

        #pragma unroll
        for (int i = 0; i < 8; ++i) {
            l_i[i] = l_i[i] * alpha[i] + ps[i];
            Oa[i] *= alpha[i];
        }

        // --- PV: O[i][lane] += sum_j p[i][j] * V[j][lane] ---------------------
        #pragma unroll 8
        for (int j = 0; j < BK; ++j) {
            const float v = Vs[(j << 6) + lane];
            #pragma unroll
            for (int i = 0; i < 8; ++i)
                Oa[i] = fmaf(__shfl(p[i], j, 64), v, Oa[i]);
        }
    }

    #pragma unroll
    for (int i = 0; i < 8; ++i)
        out[((size_t)b * SS + q0 + wave * 8 + i) * HH + lane] = Oa[i] / l_i[i];
}

// ---------------------------------------------------------------------------
extern "C" void kernel_launch(void* const* d_in, const int* in_sizes, int n_in,
                              void* d_out, int out_size, void* d_ws, size_t ws_size,
                              hipStream_t stream) {
    const float* query = (const float*)d_in[0];
    const float* key   = (const float*)d_in[1];
    const float* value = (const float*)d_in[2];
    const float* Wq    = (const float*)d_in[3];
    const float* bq    = (const float*)d_in[4];
    const float* Wk    = (const float*)d_in[5];
    const float* bk    = (const float*)d_in[6];
    const float* Wv    = (const float*)d_in[7];
    const float* bv    = (const float*)d_in[8];
    float* out = (float*)d_out;

    float* qp = (float*)d_ws;                    // 16384 x 64
    float* kp = qp + (size_t)MM * HH;
    float* vp = kp + (size_t)MM * HH;

    dim3 pgrid(MM / PM, 3);
    proj_kernel<<<pgrid, 256, 0, stream>>>(query, key, value,
                                           Wq, Wk, Wv,
                                           bq, bk, bv,
                                           qp, kp, vp);

    dim3 agrid(SS / BQ, BB);
    flash_kernel<<<agrid, 512, 0, stream>>>(qp, kp, vp, out);
}

// Round 2
// 317.198 us; speedup vs baseline: 2.4991x; 2.4991x over previous
//
#include <hip/hip_runtime.h>
#include <math.h>

#define BB 8
#define SS 2048
#define EE 1024
#define HH 64
#define MM (BB * SS)   // 16384 rows

typedef unsigned short u16;
typedef __attribute__((ext_vector_type(8))) short short8;   // 8 x bf16
typedef __attribute__((ext_vector_type(4))) float floatx4;  // mfma C/D

__device__ __forceinline__ u16 f2bf(float f) {
    union { float f; unsigned u; } a; a.f = f;
    unsigned r = a.u + 0x7fffu + ((a.u >> 16) & 1u);   // RNE
    return (u16)(r >> 16);
}

// ---------------------------------------------------------------------------
// Projection GEMM (fp32 compute, bf16 store): out[M x 64] = A[M x 1024] @ W + b
// ---------------------------------------------------------------------------
#define PM 64
#define PK 32

__global__ __launch_bounds__(256) void proj_kernel(
    const float* __restrict__ A0, const float* __restrict__ A1, const float* __restrict__ A2,
    const float* __restrict__ W0, const float* __restrict__ W1, const float* __restrict__ W2,
    const float* __restrict__ b0, const float* __restrict__ b1, const float* __restrict__ b2,
    u16* __restrict__ o0, u16* __restrict__ o1, u16* __restrict__ o2)
{
    const int which = blockIdx.y;
    const float* __restrict__ A    = (which == 0) ? A0 : (which == 1) ? A1 : A2;
    const float* __restrict__ W    = (which == 0) ? W0 : (which == 1) ? W1 : W2;
    const float* __restrict__ bias = (which == 0) ? b0 : (which == 1) ? b1 : b2;
    u16* __restrict__ out          = (which == 0) ? o0 : (which == 1) ? o1 : o2;

    __shared__ __align__(16) float As[PM][PK + 4];   // 64 x 36
    __shared__ __align__(16) float Ws[PK][HH + 4];   // 32 x 68

    const int row0 = blockIdx.x * PM;
    const int tid  = threadIdx.x;
    const int tx   = tid & 15;
    const int ty   = tid >> 4;

    float acc[4][4];
    #pragma unroll
    for (int i = 0; i < 4; ++i)
        #pragma unroll
        for (int j = 0; j < 4; ++j) acc[i][j] = 0.f;

    for (int kc = 0; kc < EE; kc += PK) {
        #pragma unroll
        for (int e4 = tid; e4 < PM * PK / 4; e4 += 256) {
            int r = e4 >> 3;
            int c = (e4 & 7) << 2;
            *(float4*)&As[r][c] = *(const float4*)&A[(size_t)(row0 + r) * EE + kc + c];
        }
        #pragma unroll
        for (int e4 = tid; e4 < PK * HH / 4; e4 += 256) {
            int r = e4 >> 4;
            int c = (e4 & 15) << 2;
            *(float4*)&Ws[r][c] = *(const float4*)&W[(size_t)(kc + r) * HH + c];
        }
        __syncthreads();

        #pragma unroll
        for (int kk = 0; kk < PK; ++kk) {
            float a[4];
            #pragma unroll
            for (int i = 0; i < 4; ++i) a[i] = As[ty * 4 + i][kk];
            const float4 w4 = *(const float4*)&Ws[kk][tx * 4];
            #pragma unroll
            for (int i = 0; i < 4; ++i) {
                acc[i][0] = fmaf(a[i], w4.x, acc[i][0]);
                acc[i][1] = fmaf(a[i], w4.y, acc[i][1]);
                acc[i][2] = fmaf(a[i], w4.z, acc[i][2]);
                acc[i][3] = fmaf(a[i], w4.w, acc[i][3]);
            }
        }
        __syncthreads();
    }

    const float4 b4 = *(const float4*)&bias[tx * 4];
    #pragma unroll
    for (int i = 0; i < 4; ++i) {
        ushort4 o;
        o.x = f2bf(acc[i][0] + b4.x);
        o.y = f2bf(acc[i][1] + b4.y);
        o.z = f2bf(acc[i][2] + b4.z);
        o.w = f2bf(acc[i][3] + b4.w);
        *(ushort4*)&out[(size_t)(row0 + ty * 4 + i) * HH + tx * 4] = o;
    }
}

// ---------------------------------------------------------------------------
// MFMA flash attention. Block = 256 thr = 4 waves: wq = wave&1 (q-tile of 16),
// ks = wave>>1 (key split: 64 of each staged 128 keys). Grid = (64, 8).
// K in LDS row-major (XOR chunk swizzle); V in LDS transposed (XOR swizzle);
// P round-trips through per-wave LDS (C-layout -> A-layout).
// ---------------------------------------------------------------------------
__global__ __launch_bounds__(256) void flash_mfma(
    const u16* __restrict__ qp, const u16* __restrict__ kp,
    const u16* __restrict__ vp, float* __restrict__ out)
{
    __shared__ __align__(16) u16 Ks[128 * 64];     // row j: 8 chunks of 8, chunk cs at cs^(j&7)
    __shared__ __align__(16) u16 Vt[64 * 128];     // row h: 16 chunks of 8 j, chunk cj at cj^(h&7)
    __shared__ __align__(16) u16 Pw[4][16 * 72];   // per-wave P, stride 72

    const int b    = blockIdx.y;
    const int q0   = blockIdx.x * 32;
    const int tid  = threadIdx.x;
    const int lane = tid & 63;
    const int wave = tid >> 6;
    const int wq   = wave & 1;
    const int ks   = wave >> 1;
    const int n    = lane & 15;
    const int g    = lane >> 4;

    // Q A-frags: A[m=lane&15][k=g*8+j]; rows q0+wq*16+m
    const u16* qrow = qp + ((size_t)b * SS + q0 + wq * 16 + n) * HH;
    const short8 qa0 = *(const short8*)(qrow + g * 8);
    const short8 qa1 = *(const short8*)(qrow + 32 + g * 8);

    floatx4 Oa[4];
    #pragma unroll
    for (int ht = 0; ht < 4; ++ht) Oa[ht] = (floatx4){0.f, 0.f, 0.f, 0.f};
    float m_i[4], l_i[4];
    #pragma unroll
    for (int r = 0; r < 4; ++r) { m_i[r] = -1e30f; l_i[r] = 0.f; }

    const u16* kb = kp + (size_t)b * SS * HH;
    const u16* vb = vp + (size_t)b * SS * HH;

    for (int t = 0; t < 16; ++t) {
        __syncthreads();
        // ---- stage K: 128 keys x 64 h, coalesced 16B chunks, XOR swizzle ----
        #pragma unroll
        for (int it = 0; it < 4; ++it) {
            int c  = it * 256 + tid;          // 0..1023 chunk id
            int j  = c >> 3, cs = c & 7;
            short8 v = *(const short8*)(kb + ((size_t)(t * 128 + j)) * HH + cs * 8);
            *(short8*)&Ks[j * 64 + ((cs ^ (j & 7)) << 3)] = v;
        }
        // ---- stage V transposed: Vt[h][j], XOR chunk swizzle ----------------
        {
            const int j0 = (tid & 31) * 4, h0 = (tid >> 5) * 8;
            short8 r0 = *(const short8*)(vb + (size_t)(t * 128 + j0 + 0) * HH + h0);
            short8 r1 = *(const short8*)(vb + (size_t)(t * 128 + j0 + 1) * HH + h0);
            short8 r2 = *(const short8*)(vb + (size_t)(t * 128 + j0 + 2) * HH + h0);
            short8 r3 = *(const short8*)(vb + (size_t)(t * 128 + j0 + 3) * HH + h0);
            #pragma unroll
            for (int i = 0; i < 8; ++i) {
                int h = h0 + i;
                ushort4 w;
                w.x = (u16)r0[i]; w.y = (u16)r1[i]; w.z = (u16)r2[i]; w.w = (u16)r3[i];
                *(ushort4*)((char*)Vt + h * 256 + (((j0 >> 3) ^ (h & 7)) << 4) + ((j0 & 4) << 1)) = w;
            }
        }
        __syncthreads();

        // ---- QK^T: S[16 q][64 keys] over my 64-key half ---------------------
        floatx4 S[4];
        #pragma unroll
        for (int nt = 0; nt < 4; ++nt) {
            const int j = ks * 64 + nt * 16 + n;     // B: col n = key j
            const short8 kb0 = *(const short8*)&Ks[j * 64 + (((0 + g) ^ (j & 7)) << 3)];
            const short8 kb1 = *(const short8*)&Ks[j * 64 + (((4 + g) ^ (j & 7)) << 3)];
            floatx4 acc = (floatx4){0.f, 0.f, 0.f, 0.f};
            acc = __builtin_amdgcn_mfma_f32_16x16x32_bf16(qa0, kb0, acc, 0, 0, 0);
            acc = __builtin_amdgcn_mfma_f32_16x16x32_bf16(qa1, kb1, acc, 0, 0, 0);
            S[nt] = acc;
        }

        // ---- online softmax (rows r = g*4+reg, cols nt*16+n) ----------------
        float mx[4];
        #pragma unroll
        for (int r = 0; r < 4; ++r) mx[r] = -1e30f;
        #pragma unroll
        for (int nt = 0; nt < 4; ++nt)
            #pragma unroll
            for (int r = 0; r < 4; ++r) {
                S[nt][r] *= 0.125f;
                mx[r] = fmaxf(mx[r], S[nt][r]);
            }
        #pragma unroll
        for (int off = 8; off >= 1; off >>= 1)
            #pragma unroll
            for (int r = 0; r < 4; ++r)
                mx[r] = fmaxf(mx[r], __shfl_xor(mx[r], off, 64));

        float alpha[4], ps[4];
        #pragma unroll
        for (int r = 0; r < 4; ++r) {
            const float Mn = fmaxf(m_i[r], mx[r]);
            alpha[r] = __expf(m_i[r] - Mn);
            m_i[r]   = Mn;
            ps[r]    = 0.f;
        }
        float p[4][4];
        #pragma unroll
        for (int nt = 0; nt < 4; ++nt)
            #pragma unroll
            for (int r = 0; r < 4; ++r) {
                p[nt][r] = __expf(S[nt][r] - m_i[r]);
                ps[r] += p[nt][r];
            }
        #pragma unroll
        for (int off = 8; off >= 1; off >>= 1)
            #pragma unroll
            for (int r = 0; r < 4; ++r)
                ps[r] += __shfl_xor(ps[r], off, 64);
        #pragma unroll
        for (int r = 0; r < 4; ++r) l_i[r] = l_i[r] * alpha[r] + ps[r];
        #pragma unroll
        for (int ht = 0; ht < 4; ++ht)
            #pragma unroll
            for (int r = 0; r < 4; ++r) Oa[ht][r] *= alpha[r];

        // ---- P: C-layout -> LDS -> A-layout ---------------------------------
        #pragma unroll
        for (int nt = 0; nt < 4; ++nt)
            #pragma unroll
            for (int r = 0; r < 4; ++r)
                Pw[wave][(g * 4 + r) * 72 + nt * 16 + n] = f2bf(p[nt][r]);

        const short8 pa0 = *(const short8*)&Pw[wave][n * 72 + g * 8];
        const short8 pa1 = *(const short8*)&Pw[wave][n * 72 + 32 + g * 8];

        // ---- PV: O[16 q][64 h] += P[16 x 64keys] @ V[64keys x 64h] ----------
        #pragma unroll
        for (int ht = 0; ht < 4; ++ht) {
            const int h = ht * 16 + n;               // B: col n = head h
            const int cj0 = ks * 8 + 0 + g;          // j-chunk for k-step 0
            const int cj1 = ks * 8 + 4 + g;          // j-chunk for k-step 1
            const short8 vb0 = *(const short8*)((const char*)Vt + h * 256 + ((cj0 ^ (h & 7)) << 4));
            const short8 vb1 = *(const short8*)((const char*)Vt + h * 256 + ((cj1 ^ (h & 7)) << 4));
            Oa[ht] = __builtin_amdgcn_mfma_f32_16x16x32_bf16(pa0, vb0, Oa[ht], 0, 0, 0);
            Oa[ht] = __builtin_amdgcn_mfma_f32_16x16x32_bf16(pa1, vb1, Oa[ht], 0, 0, 0);
        }
    }

    // ---- combine the two key-splits via LDS (reuse Ks) ----------------------
    __syncthreads();
    float* Cb = (float*)Ks;                 // [wq][16][68]
    float* Cm = Cb + 2 * 16 * 68;           // [wq][16]
    float* Cl = Cm + 32;
    if (ks == 1) {
        #pragma unroll
        for (int ht = 0; ht < 4; ++ht)
            #pragma unroll
            for (int r = 0; r < 4; ++r)
                Cb[(wq * 16 + g * 4 + r) * 68 + ht * 16 + n] = Oa[ht][r];
        if (n == 0)
            #pragma unroll
            for (int r = 0; r < 4; ++r) {
                Cm[wq * 16 + g * 4 + r] = m_i[r];
                Cl[wq * 16 + g * 4 + r] = l_i[r];
            }
    }
    __syncthreads();
    if (ks == 0) {
        float a0[4], a1[4], linv[4];
        #pragma unroll
        for (int r = 0; r < 4; ++r) {
            const int m = g * 4 + r;
            const float m1 = Cm[wq * 16 + m], l1 = Cl[wq * 16 + m];
            const float M  = fmaxf(m_i[r], m1);
            const float e0 = __expf(m_i[r] - M), e1 = __expf(m1 - M);
            a0[r] = e0; a1[r] = e1;
            linv[r] = 1.f / (l_i[r] * e0 + l1 * e1);
        }
        #pragma unroll
        for (int ht = 0; ht < 4; ++ht)
            #pragma unroll
            for (int r = 0; r < 4; ++r) {
                const float o1 = Cb[(wq * 16 + g * 4 + r) * 68 + ht * 16 + n];
                const float v  = (Oa[ht][r] * a0[r] + o1 * a1[r]) * linv[r];
                out[((size_t)b * SS + q0 + wq * 16 + g * 4 + r) * HH + ht * 16 + n] = v;
            }
    }
}

// ---------------------------------------------------------------------------
extern "C" void kernel_launch(void* const* d_in, const int* in_sizes, int n_in,
                              void* d_out, int out_size, void* d_ws, size_t ws_size,
                              hipStream_t stream) {
    const float* query = (const float*)d_in[0];
    const float* key   = (const float*)d_in[1];
    const float* value = (const float*)d_in[2];
    const float* Wq    = (const float*)d_in[3];
    const float* bq    = (const float*)d_in[4];
    const float* Wk    = (const float*)d_in[5];
    const float* bk    = (const float*)d_in[6];
    const float* Wv    = (const float*)d_in[7];
    const float* bv    = (const float*)d_in[8];
    float* out = (float*)d_out;

    u16* qp = (u16*)d_ws;                        // 16384 x 64 bf16
    u16* kp = qp + (size_t)MM * HH;
    u16* vp = kp + (size_t)MM * HH;

    dim3 pgrid(MM / PM, 3);
    proj_kernel<<<pgrid, 256, 0, stream>>>(query, key, value,
                                           Wq, Wk, Wv,
                                           bq, bk, bv,
                                           qp, kp, vp);

    dim3 agrid(SS / 32, BB);
    flash_mfma<<<agrid, 256, 0, stream>>>(qp, kp, vp, out);
}

// Round 3
// 286.407 us; speedup vs baseline: 2.7678x; 1.1075x over previous
//
#include <hip/hip_runtime.h>
#include <math.h>

#define BB 8
#define SS 2048
#define EE 1024
#define HH 64
#define MM (BB * SS)   // 16384 rows

typedef unsigned short u16;
typedef __attribute__((ext_vector_type(8))) short short8;   // 8 x bf16
typedef __attribute__((ext_vector_type(4))) float floatx4;  // mfma C/D

__device__ __forceinline__ u16 f2bf(float f) {
    union { float f; unsigned u; } a; a.f = f;
    unsigned r = a.u + 0x7fffu + ((a.u >> 16) & 1u);   // RNE
    return (u16)(r >> 16);
}

// Split two fp32 into packed bf16 hi (truncated) and bf16 lo (residual, truncated).
// hi+lo reproduces fp32 to ~2^-16 relative.
__device__ __forceinline__ void split2(float f0, float f1, unsigned& hp, unsigned& lp) {
    union { float f; unsigned u; } a0, a1, h0, h1, l0, l1;
    a0.f = f0; a1.f = f1;
    h0.u = a0.u & 0xffff0000u;
    h1.u = a1.u & 0xffff0000u;
    l0.f = f0 - h0.f;
    l1.f = f1 - h1.f;
    hp = __builtin_amdgcn_perm(a1.u, a0.u, 0x07060302u);  // [hi16(f1)|hi16(f0)]
    lp = __builtin_amdgcn_perm(l1.u, l0.u, 0x07060302u);
}

// ---------------------------------------------------------------------------
// Projection GEMM via bf16 MFMA + hi/lo compensation (3 passes).
// out[M x 64] = A[M x 1024] @ W[1024 x 64] + b.  Tile 128 rows, BK=64.
// Block 256 thr = 4 waves; wave w -> rows [w*32, w*32+32) = 2 m-tiles x 4 n-tiles.
// ---------------------------------------------------------------------------
#define BM 128
#define BKp 64

__global__ __launch_bounds__(256) void proj_mfma(
    const float* __restrict__ A0, const float* __restrict__ A1, const float* __restrict__ A2,
    const float* __restrict__ W0, const float* __restrict__ W1, const float* __restrict__ W2,
    const float* __restrict__ b0, const float* __restrict__ b1, const float* __restrict__ b2,
    u16* __restrict__ o0, u16* __restrict__ o1, u16* __restrict__ o2)
{
    const int which = blockIdx.y;
    const float* __restrict__ A    = (which == 0) ? A0 : (which == 1) ? A1 : A2;
    const float* __restrict__ W    = (which == 0) ? W0 : (which == 1) ? W1 : W2;
    const float* __restrict__ bias = (which == 0) ? b0 : (which == 1) ? b1 : b2;
    u16* __restrict__ out          = (which == 0) ? o0 : (which == 1) ? o1 : o2;

    // stride 72 shorts = 144 B: row r starts at bank 4r%32 -> 2-way aliasing (free)
    __shared__ __align__(16) u16 Ah[BM][72], Al[BM][72];   // 18432 B each
    __shared__ __align__(16) u16 Wh[64][72], Wl[64][72];   // 9216 B each

    const int tid  = threadIdx.x;
    const int lane = tid & 63;
    const int wave = tid >> 6;
    const int n    = lane & 15;
    const int g    = lane >> 4;
    const int row0 = blockIdx.x * BM;

    // staging assignments
    const int ar = tid >> 1;             // A row 0..127
    const int ak = (tid & 1) * 32;       // k-half
    const int wk = (tid >> 4) * 4;       // W k rows wk..wk+3
    const int wn = (tid & 15) * 4;       // W cols wn..wn+3

    floatx4 acc[2][4];
    #pragma unroll
    for (int mt = 0; mt < 2; ++mt)
        #pragma unroll
        for (int nt = 0; nt < 4; ++nt) acc[mt][nt] = (floatx4){0.f, 0.f, 0.f, 0.f};

    for (int kc = 0; kc < EE; kc += BKp) {
        // ---- stage A: 128 x 64 fp32 -> bf16 hi/lo -------------------------
        const float* ap = A + (size_t)(row0 + ar) * EE + kc + ak;
        float4 av[8];
        #pragma unroll
        for (int i = 0; i < 8; ++i) av[i] = *(const float4*)(ap + i * 4);

        __syncthreads();   // previous iter's frags consumed

        #pragma unroll
        for (int i = 0; i < 4; ++i) {     // 8 elems per group -> one b128 hi + lo
            unsigned hp0, lp0, hp1, lp1, hp2, lp2, hp3, lp3;
            split2(av[2*i].x,   av[2*i].y,   hp0, lp0);
            split2(av[2*i].z,   av[2*i].w,   hp1, lp1);
            split2(av[2*i+1].x, av[2*i+1].y, hp2, lp2);
            split2(av[2*i+1].z, av[2*i+1].w, hp3, lp3);
            uint4 h4 = {hp0, hp1, hp2, hp3};
            uint4 l4 = {lp0, lp1, lp2, lp3};
            *(uint4*)&Ah[ar][ak + i * 8] = h4;
            *(uint4*)&Al[ar][ak + i * 8] = l4;
        }

        // ---- stage W transposed: Wt[n][k] hi/lo ---------------------------
        float4 wv[4];
        #pragma unroll
        for (int i = 0; i < 4; ++i)
            wv[i] = *(const float4*)&W[(size_t)(kc + wk + i) * HH + wn];
        #pragma unroll
        for (int j = 0; j < 4; ++j) {
            const float e0 = (&wv[0].x)[j], e1 = (&wv[1].x)[j],
                        e2 = (&wv[2].x)[j], e3 = (&wv[3].x)[j];
            unsigned hp0, lp0, hp1, lp1;
            split2(e0, e1, hp0, lp0);
            split2(e2, e3, hp1, lp1);
            uint2 h2 = {hp0, hp1};
            uint2 l2 = {lp0, lp1};
            *(uint2*)&Wh[wn + j][wk] = h2;
            *(uint2*)&Wl[wn + j][wk] = l2;
        }
        __syncthreads();

        // ---- compute: 2 k-steps of 32 -------------------------------------
        #pragma unroll
        for (int ks = 0; ks < 2; ++ks) {
            short8 ahf[2], alf[2], whf[4], wlf[4];
            #pragma unroll
            for (int mt = 0; mt < 2; ++mt) {
                ahf[mt] = *(const short8*)&Ah[wave * 32 + mt * 16 + n][ks * 32 + g * 8];
                alf[mt] = *(const short8*)&Al[wave * 32 + mt * 16 + n][ks * 32 + g * 8];
            }
            #pragma unroll
            for (int nt = 0; nt < 4; ++nt) {
                whf[nt] = *(const short8*)&Wh[nt * 16 + n][ks * 32 + g * 8];
                wlf[nt] = *(const short8*)&Wl[nt * 16 + n][ks * 32 + g * 8];
            }
            #pragma unroll
            for (int mt = 0; mt < 2; ++mt)
                #pragma unroll
                for (int nt = 0; nt < 4; ++nt) {
                    acc[mt][nt] = __builtin_amdgcn_mfma_f32_16x16x32_bf16(ahf[mt], whf[nt], acc[mt][nt], 0, 0, 0);
                    acc[mt][nt] = __builtin_amdgcn_mfma_f32_16x16x32_bf16(alf[mt], whf[nt], acc[mt][nt], 0, 0, 0);
                    acc[mt][nt] = __builtin_amdgcn_mfma_f32_16x16x32_bf16(ahf[mt], wlf[nt], acc[mt][nt], 0, 0, 0);
                }
        }
    }

    // ---- epilogue: bias + bf16 store -------------------------------------
    #pragma unroll
    for (int mt = 0; mt < 2; ++mt)
        #pragma unroll
        for (int nt = 0; nt < 4; ++nt) {
            const float bv = bias[nt * 16 + n];
            #pragma unroll
            for (int r = 0; r < 4; ++r) {
                const int row = row0 + wave * 32 + mt * 16 + g * 4 + r;
                out[(size_t)row * HH + nt * 16 + n] = f2bf(acc[mt][nt][r] + bv);
            }
        }
}

// ---------------------------------------------------------------------------
// MFMA flash attention, double-buffered 64-key tiles, 1 barrier/iter.
// Block 256 thr = 4 waves: wq = wave&1 (16-q tile), ks = wave>>1 (32-key half).
// Grid (64, 8). Next tile loaded to regs before compute, written after.
// ---------------------------------------------------------------------------
__global__ __launch_bounds__(256) void flash_mfma(
    const u16* __restrict__ qp, const u16* __restrict__ kp,
    const u16* __restrict__ vp, float* __restrict__ out)
{
    __shared__ __align__(16) u16 Ks[2][64 * 64];   // row j: 8 chunks, chunk cs at cs^(j&7)
    __shared__ __align__(16) u16 Vt[2][64 * 64];   // row h: 8 j-chunks, chunk cj at cj^(h&7)
    __shared__ __align__(16) u16 Pw[4][16 * 72];

    const int b    = blockIdx.y;
    const int q0   = blockIdx.x * 32;
    const int tid  = threadIdx.x;
    const int lane = tid & 63;
    const int wave = tid >> 6;
    const int wq   = wave & 1;
    const int ks   = wave >> 1;
    const int n    = lane & 15;
    const int g    = lane >> 4;

    const u16* qrow = qp + ((size_t)b * SS + q0 + wq * 16 + n) * HH;
    const short8 qa0 = *(const short8*)(qrow + g * 8);
    const short8 qa1 = *(const short8*)(qrow + 32 + g * 8);

    floatx4 Oa[4];
    #pragma unroll
    for (int ht = 0; ht < 4; ++ht) Oa[ht] = (floatx4){0.f, 0.f, 0.f, 0.f};
    float m_i[4], l_i[4];
    #pragma unroll
    for (int r = 0; r < 4; ++r) { m_i[r] = -1e30f; l_i[r] = 0.f; }

    const u16* kb = kp + (size_t)b * SS * HH;
    const u16* vb = vp + (size_t)b * SS * HH;

    // staging indices (tid-only)
    const int jK0 = tid >> 3, jK1 = 32 + (tid >> 3), cs = tid & 7;
    const int jV  = (tid & 15) * 4, hV = (tid >> 4) * 4;

    short8  kr0, kr1;
    ushort4 vr0, vr1, vr2, vr3;

    // ---- prologue: stage tile 0 into buf 0 --------------------------------
    kr0 = *(const short8*)(kb + (size_t)jK0 * HH + cs * 8);
    kr1 = *(const short8*)(kb + (size_t)jK1 * HH + cs * 8);
    vr0 = *(const ushort4*)(vb + (size_t)(jV + 0) * HH + hV);
    vr1 = *(const ushort4*)(vb + (size_t)(jV + 1) * HH + hV);
    vr2 = *(const ushort4*)(vb + (size_t)(jV + 2) * HH + hV);
    vr3 = *(const ushort4*)(vb + (size_t)(jV + 3) * HH + hV);
    {
        *(short8*)&Ks[0][jK0 * 64 + ((cs ^ (jK0 & 7)) << 3)] = kr0;
        *(short8*)&Ks[0][jK1 * 64 + ((cs ^ (jK1 & 7)) << 3)] = kr1;
        const u16* a0 = (const u16*)&vr0; const u16* a1 = (const u16*)&vr1;
        const u16* a2 = (const u16*)&vr2; const u16* a3 = (const u16*)&vr3;
        #pragma unroll
        for (int i = 0; i < 4; ++i) {
            const int h = hV + i;
            ushort4 w; w.x = a0[i]; w.y = a1[i]; w.z = a2[i]; w.w = a3[i];
            *(ushort4*)((char*)&Vt[0][0] + h * 128 + (((jV >> 3) ^ (h & 7)) << 4) + ((jV & 4) << 1)) = w;
        }
    }
    __syncthreads();

    for (int t = 0; t < SS / 64; ++t) {
        const int cur = t & 1;

        // ---- issue next tile's global loads (latency hides under compute) --
        if (t + 1 < SS / 64) {
            const size_t kt = (size_t)(t + 1) * 64;
            kr0 = *(const short8*)(kb + (kt + jK0) * HH + cs * 8);
            kr1 = *(const short8*)(kb + (kt + jK1) * HH + cs * 8);
            vr0 = *(const ushort4*)(vb + (kt + jV + 0) * HH + hV);
            vr1 = *(const ushort4*)(vb + (kt + jV + 1) * HH + hV);
            vr2 = *(const ushort4*)(vb + (kt + jV + 2) * HH + hV);
            vr3 = *(const ushort4*)(vb + (kt + jV + 3) * HH + hV);
        }

        // ---- QK^T: S[16 q][32 keys] (my half) ------------------------------
        floatx4 S[2];
        #pragma unroll
        for (int nt = 0; nt < 2; ++nt) {
            const int j = ks * 32 + nt * 16 + n;
            const short8 kf0 = *(const short8*)&Ks[cur][j * 64 + (((0 + g) ^ (j & 7)) << 3)];
            const short8 kf1 = *(const short8*)&Ks[cur][j * 64 + (((4 + g) ^ (j & 7)) << 3)];
            floatx4 a = (floatx4){0.f, 0.f, 0.f, 0.f};
            a = __builtin_amdgcn_mfma_f32_16x16x32_bf16(qa0, kf0, a, 0, 0, 0);
            a = __builtin_amdgcn_mfma_f32_16x16x32_bf16(qa1, kf1, a, 0, 0, 0);
            S[nt] = a;
        }

        // ---- online softmax ------------------------------------------------
        float mx[4];
        #pragma unroll
        for (int r = 0; r < 4; ++r) mx[r] = -1e30f;
        #pragma unroll
        for (int nt = 0; nt < 2; ++nt)
            #pragma unroll
            for (int r = 0; r < 4; ++r) {
                S[nt][r] *= 0.125f;
                mx[r] = fmaxf(mx[r], S[nt][r]);
            }
        #pragma unroll
        for (int off = 8; off >= 1; off >>= 1)
            #pragma unroll
            for (int r = 0; r < 4; ++r)
                mx[r] = fmaxf(mx[r], __shfl_xor(mx[r], off, 64));

        float alpha[4], ps[4];
        #pragma unroll
        for (int r = 0; r < 4; ++r) {
            const float Mn = fmaxf(m_i[r], mx[r]);
            alpha[r] = __expf(m_i[r] - Mn);
            m_i[r]   = Mn;
            ps[r]    = 0.f;
        }
        float p[2][4];
        #pragma unroll
        for (int nt = 0; nt < 2; ++nt)
            #pragma unroll
            for (int r = 0; r < 4; ++r) {
                p[nt][r] = __expf(S[nt][r] - m_i[r]);
                ps[r] += p[nt][r];
            }
        #pragma unroll
        for (int off = 8; off >= 1; off >>= 1)
            #pragma unroll
            for (int r = 0; r < 4; ++r)
                ps[r] += __shfl_xor(ps[r], off, 64);
        #pragma unroll
        for (int r = 0; r < 4; ++r) l_i[r] = l_i[r] * alpha[r] + ps[r];
        #pragma unroll
        for (int ht = 0; ht < 4; ++ht)
            #pragma unroll
            for (int r = 0; r < 4; ++r) Oa[ht][r] *= alpha[r];

        // ---- P: C-layout -> LDS -> A-layout (per-wave, no barrier needed) --
        #pragma unroll
        for (int nt = 0; nt < 2; ++nt)
            #pragma unroll
            for (int r = 0; r < 4; ++r)
                Pw[wave][(g * 4 + r) * 72 + nt * 16 + n] = f2bf(p[nt][r]);
        const short8 pa = *(const short8*)&Pw[wave][n * 72 + g * 8];

        // ---- PV: O[16 q][64 h] += P[16 x 32] @ V[32 x 64] ------------------
        #pragma unroll
        for (int ht = 0; ht < 4; ++ht) {
            const int h = ht * 16 + n;
            const short8 vf = *(const short8*)((const char*)&Vt[cur][0] + h * 128 +
                                               ((((ks << 2) + g) ^ (h & 7)) << 4));
            Oa[ht] = __builtin_amdgcn_mfma_f32_16x16x32_bf16(pa, vf, Oa[ht], 0, 0, 0);
        }

        // ---- write next tile into the other buffer -------------------------
        if (t + 1 < SS / 64) {
            const int nx = cur ^ 1;
            *(short8*)&Ks[nx][jK0 * 64 + ((cs ^ (jK0 & 7)) << 3)] = kr0;
            *(short8*)&Ks[nx][jK1 * 64 + ((cs ^ (jK1 & 7)) << 3)] = kr1;
            const u16* a0 = (const u16*)&vr0; const u16* a1 = (const u16*)&vr1;
            const u16* a2 = (const u16*)&vr2; const u16* a3 = (const u16*)&vr3;
            #pragma unroll
            for (int i = 0; i < 4; ++i) {
                const int h = hV + i;
                ushort4 w; w.x = a0[i]; w.y = a1[i]; w.z = a2[i]; w.w = a3[i];
                *(ushort4*)((char*)&Vt[nx][0] + h * 128 + (((jV >> 3) ^ (h & 7)) << 4) + ((jV & 4) << 1)) = w;
            }
        }
        __syncthreads();
    }

    // ---- combine the two key-splits via LDS (reuse Ks) ----------------------
    float* Cb = (float*)&Ks[0][0];          // [wq][16][68]
    float* Cm = Cb + 2 * 16 * 68;           // [wq][16]
    float* Cl = Cm + 32;
    if (ks == 1) {
        #pragma unroll
        for (int ht = 0; ht < 4; ++ht)
            #pragma unroll
            for (int r = 0; r < 4; ++r)
                Cb[(wq * 16 + g * 4 + r) * 68 + ht * 16 + n] = Oa[ht][r];
        if (n == 0)
            #pragma unroll
            for (int r = 0; r < 4; ++r) {
                Cm[wq * 16 + g * 4 + r] = m_i[r];
                Cl[wq * 16 + g * 4 + r] = l_i[r];
            }
    }
    __syncthreads();
    if (ks == 0) {
        float a0v[4], a1v[4], linv[4];
        #pragma unroll
        for (int r = 0; r < 4; ++r) {
            const int m = g * 4 + r;
            const float m1 = Cm[wq * 16 + m], l1 = Cl[wq * 16 + m];
            const float M  = fmaxf(m_i[r], m1);
            const float e0 = __expf(m_i[r] - M), e1 = __expf(m1 - M);
            a0v[r] = e0; a1v[r] = e1;
            linv[r] = 1.f / (l_i[r] * e0 + l1 * e1);
        }
        #pragma unroll
        for (int ht = 0; ht < 4; ++ht)
            #pragma unroll
            for (int r = 0; r < 4; ++r) {
                const float o1 = Cb[(wq * 16 + g * 4 + r) * 68 + ht * 16 + n];
                const float v  = (Oa[ht][r] * a0v[r] + o1 * a1v[r]) * linv[r];
                out[((size_t)b * SS + q0 + wq * 16 + g * 4 + r) * HH + ht * 16 + n] = v;
            }
    }
}

// ---------------------------------------------------------------------------
extern "C" void kernel_launch(void* const* d_in, const int* in_sizes, int n_in,
                              void* d_out, int out_size, void* d_ws, size_t ws_size,
                              hipStream_t stream) {
    const float* query = (const float*)d_in[0];
    const float* key   = (const float*)d_in[1];
    const float* value = (const float*)d_in[2];
    const float* Wq    = (const float*)d_in[3];
    const float* bq    = (const float*)d_in[4];
    const float* Wk    = (const float*)d_in[5];
    const float* bk    = (const float*)d_in[6];
    const float* Wv    = (const float*)d_in[7];
    const float* bv    = (const float*)d_in[8];
    float* out = (float*)d_out;

    u16* qp = (u16*)d_ws;                        // 16384 x 64 bf16 each
    u16* kp = qp + (size_t)MM * HH;
    u16* vp = kp + (size_t)MM * HH;

    dim3 pgrid(MM / BM, 3);
    proj_mfma<<<pgrid, 256, 0, stream>>>(query, key, value,
                                         Wq, Wk, Wv,
                                         bq, bk, bv,
                                         qp, kp, vp);

    dim3 agrid(SS / 32, BB);
    flash_mfma<<<agrid, 256, 0, stream>>>(qp, kp, vp, out);
}